// Round 6
// baseline (59.423 us; speedup 1.0000x reference)
//
#include <hip/hip_runtime.h>

#define RES   256
#define NANG  180
#define NRAYS 256
#define NPIX  (RES * RES)
#define OUTP  (NANG * NRAYS)

#define PITCH 258                    // padded row pitch (float4 elems)
#define PADN  (PITCH * PITCH)        // 66564 padded pixels

#define PLANE (NANG * NRAYS)         // 46080 (full angle set now — uniform path)
#define NSG   2                      // step groups (128 steps each)
#define PART_ELEMS (NSG * 4 * PLANE) // [sg][batch][angle][ray]
#define RED_ELEMS  (4 * PLANE)

// grid: 180 angles x 4 ray-groups(64) x 2 step-groups(128) = 1440 blocks
#define TOTAL_BLOCKS (NANG * 4 * NSG)

// ---- pre-pass: imgs[4][256][256] -> zero-padded batch-interleaved float4[258][258]
__global__ __launch_bounds__(256) void pad_interleave(
    const float* __restrict__ imgs, float4* __restrict__ timg)
{
    const int idx = blockIdx.x * 256 + threadIdx.x;
    if (idx >= PADN) return;
    const int y = idx / PITCH, x = idx - y * PITCH;
    float4 v = make_float4(0.f, 0.f, 0.f, 0.f);
    if (x >= 1 && x <= RES && y >= 1 && y <= RES) {
        const int s = (y - 1) * RES + (x - 1);
        v = make_float4(imgs[s], imgs[NPIX + s], imgs[2 * NPIX + s], imgs[3 * NPIX + s]);
    }
    timg[idx] = v;
}

struct Geom { float srx, sry, ddx, ddy, scale; };

__device__ __forceinline__ Geom make_geom(const float* __restrict__ angles,
                                          const float* __restrict__ rays,
                                          int a, int r)
{
    float sn, cs;
    sincosf(angles[a], &sn, &cs);
    const float4 ray = reinterpret_cast<const float4*>(rays)[r];
    const float dxr = ray.z - ray.x, dyr = ray.w - ray.y;
    const float len = sqrtf(dxr * dxr + dyr * dyr);
    Geom g;
    g.srx = cs * ray.x - sn * ray.y + 127.5f;
    g.sry = sn * ray.x + cs * ray.y + 127.5f;
    g.ddx = (cs * ray.z - sn * ray.w + 127.5f) - g.srx;
    g.ddy = (sn * ray.z + cs * ray.w + 127.5f) - g.sry;
    g.scale = len * (1.0f / RES);
    return g;
}

// padded bilinear sample: no validity checks, no clamps (border is zero)
__device__ __forceinline__ void sampleP(
    const float4* __restrict__ timg, const Geom& g, int k,
    float& a0, float& a1, float& a2, float& a3)
{
    const float t  = ((float)k + 0.5f) * (1.0f / RES);
    const float fx = fmaf(t, g.ddx, g.srx);
    const float fy = fmaf(t, g.ddy, g.sry);
    const float x0f = floorf(fx), y0f = floorf(fy);
    const float wx = fx - x0f, wy = fy - y0f;

    const int idx = (int)y0f * PITCH + (int)x0f + (PITCH + 1);
    const float4 c00 = timg[idx];
    const float4 c01 = timg[idx + 1];
    const float4 c10 = timg[idx + PITCH];
    const float4 c11 = timg[idx + PITCH + 1];

    const float w11 = wx * wy;
    const float w01 = wx - w11;
    const float w10 = wy - w11;
    const float w00 = (1.0f - wx) - w10;

    a0 = fmaf(w00, c00.x, fmaf(w01, c01.x, fmaf(w10, c10.x, fmaf(w11, c11.x, a0))));
    a1 = fmaf(w00, c00.y, fmaf(w01, c01.y, fmaf(w10, c10.y, fmaf(w11, c11.y, a1))));
    a2 = fmaf(w00, c00.z, fmaf(w01, c01.z, fmaf(w10, c10.z, fmaf(w11, c11.z, a2))));
    a3 = fmaf(w00, c00.w, fmaf(w01, c01.w, fmaf(w10, c10.w, fmaf(w11, c11.w, a3))));
}

// Universal kernel: every wave is an 8-ray x 8-step 2D tile (compact gather
// footprint at ALL angles). Block = 8 waves = 64 rays x 128-step window.
__global__ __launch_bounds__(512) void radon_main(
    const float4* __restrict__ timg,
    const float*  __restrict__ angles,
    const float*  __restrict__ rays,
    float*        __restrict__ part)
{
    const int bid = blockIdx.x;
    const int a   = bid >> 3;            // 0..179
    const int rg  = (bid >> 1) & 3;      // ray group of 64
    const int sg  = bid & 1;             // step group of 128

    const int tid  = threadIdx.x;
    const int w    = tid >> 6;           // wave 0..7
    const int lane = tid & 63;
    const int rsub = lane >> 3;          // ray within wave tile 0..7
    const int k    = lane & 7;           // step phase 0..7

    const int r = rg * 64 + w * 8 + rsub;

    const Geom g = make_geom(angles, rays, a, r);
    float a0 = 0.f, a1 = 0.f, a2 = 0.f, a3 = 0.f;

    const int k0 = sg * 128 + k;
#pragma unroll
    for (int j = 0; j < 16; ++j)
        sampleP(timg, g, k0 + j * 8, a0, a1, a2, a3);

    // reduce over the 8-step phase octet (lanes differing in bits 0..2)
#pragma unroll
    for (int m = 1; m < 8; m <<= 1) {
        a0 += __shfl_xor(a0, m, 64);
        a1 += __shfl_xor(a1, m, 64);
        a2 += __shfl_xor(a2, m, 64);
        a3 += __shfl_xor(a3, m, 64);
    }

    if (k == 0) {
        float* p = part + (size_t)sg * 4 * PLANE;
        const int base = a * NRAYS + r;
        p[0 * PLANE + base] = a0 * g.scale;
        p[1 * PLANE + base] = a1 * g.scale;
        p[2 * PLANE + base] = a2 * g.scale;
        p[3 * PLANE + base] = a3 * g.scale;
    }
}

// out[b][a][r] = sum over the 2 step-group partials
__global__ __launch_bounds__(256) void radon_reduce(
    const float* __restrict__ part, float* __restrict__ out)
{
    const int i = blockIdx.x * 256 + threadIdx.x;
    if (i >= RED_ELEMS) return;
    out[i] = part[i] + part[4 * PLANE + i];
}

// ---- fallback (no workspace): simple clamped per-ray kernel, known-correct
__global__ __launch_bounds__(256) void radon_simple(
    const float* __restrict__ imgs,
    const float* __restrict__ angles,
    const float* __restrict__ rays,
    float* __restrict__ out)
{
    const int a = blockIdx.x;
    const int r = threadIdx.x;
    const Geom g = make_geom(angles, rays, a, r);
    float a0 = 0.f, a1 = 0.f, a2 = 0.f, a3 = 0.f;
    for (int k = 0; k < RES; ++k) {
        const float t  = ((float)k + 0.5f) * (1.0f / RES);
        const float fx = fmaf(t, g.ddx, g.srx);
        const float fy = fmaf(t, g.ddy, g.sry);
        const float x0f = floorf(fx), y0f = floorf(fy);
        const float wx = fx - x0f, wy = fy - y0f;
        const int x0 = (int)x0f, y0 = (int)y0f;
        const bool vx0 = (unsigned)x0 < (unsigned)RES;
        const bool vx1 = (unsigned)(x0 + 1) < (unsigned)RES;
        const bool vy0 = (unsigned)y0 < (unsigned)RES;
        const bool vy1 = (unsigned)(y0 + 1) < (unsigned)RES;
        const int x0c = min(max(x0, 0), RES - 1), x1c = min(max(x0 + 1, 0), RES - 1);
        const int y0c = min(max(y0, 0), RES - 1), y1c = min(max(y0 + 1, 0), RES - 1);
        const float omwx = 1.0f - wx, omwy = 1.0f - wy;
        const float w00 = (vx0 && vy0) ? omwx * omwy : 0.f;
        const float w01 = (vx1 && vy0) ? wx * omwy : 0.f;
        const float w10 = (vx0 && vy1) ? omwx * wy : 0.f;
        const float w11 = (vx1 && vy1) ? wx * wy : 0.f;
        const int i00 = y0c * RES + x0c, i01 = y0c * RES + x1c;
        const int i10 = y1c * RES + x0c, i11 = y1c * RES + x1c;
        a0 = fmaf(w00, imgs[i00], fmaf(w01, imgs[i01], fmaf(w10, imgs[i10], fmaf(w11, imgs[i11], a0))));
        a1 = fmaf(w00, imgs[NPIX + i00], fmaf(w01, imgs[NPIX + i01], fmaf(w10, imgs[NPIX + i10], fmaf(w11, imgs[NPIX + i11], a1))));
        a2 = fmaf(w00, imgs[2 * NPIX + i00], fmaf(w01, imgs[2 * NPIX + i01], fmaf(w10, imgs[2 * NPIX + i10], fmaf(w11, imgs[2 * NPIX + i11], a2))));
        a3 = fmaf(w00, imgs[3 * NPIX + i00], fmaf(w01, imgs[3 * NPIX + i01], fmaf(w10, imgs[3 * NPIX + i10], fmaf(w11, imgs[3 * NPIX + i11], a3))));
    }
    const int base = a * NRAYS + r;
    out[0 * OUTP + base] = a0 * g.scale;
    out[1 * OUTP + base] = a1 * g.scale;
    out[2 * OUTP + base] = a2 * g.scale;
    out[3 * OUTP + base] = a3 * g.scale;
}

extern "C" void kernel_launch(void* const* d_in, const int* in_sizes, int n_in,
                              void* d_out, int out_size, void* d_ws, size_t ws_size,
                              hipStream_t stream) {
    const float* imgs   = (const float*)d_in[0];
    const float* angles = (const float*)d_in[1];
    const float* rays   = (const float*)d_in[2];
    float* out = (float*)d_out;

    const size_t timg_bytes = (size_t)PADN * sizeof(float4);
    const size_t need = timg_bytes + (size_t)PART_ELEMS * sizeof(float);

    if (ws_size >= need) {
        float4* timg = (float4*)d_ws;
        float*  part = (float*)((char*)d_ws + timg_bytes);
        pad_interleave<<<(PADN + 255) / 256, 256, 0, stream>>>(imgs, timg);
        radon_main<<<TOTAL_BLOCKS, 512, 0, stream>>>(timg, angles, rays, part);
        radon_reduce<<<(RED_ELEMS + 255) / 256, 256, 0, stream>>>(part, out);
    } else {
        radon_simple<<<NANG, NRAYS, 0, stream>>>(imgs, angles, rays, out);
    }
}

// Round 7
// 35.672 us; speedup vs baseline: 1.6658x; 1.6658x over previous
//
#include <hip/hip_runtime.h>

#define RES   256
#define NANG  180
#define NRAYS 256
#define NPIX  (RES * RES)
#define OUTP  (NANG * NRAYS)

#define PITCH 258                    // padded row pitch (uint4 elems)
#define PADN  (PITCH * PITCH)        // 66564 padded pixels

#define STEEP_BLOCKS   (90 * 16)     // 90 angles x 16 ray-quads(16 rays: 8 waves x 2 rays)
#define SHALLOW_BLOCKS (90 * 16)     // 90 angles x 4 raygroups(64) x 4 stepgroups(64)
#define TOTAL_BLOCKS   (STEEP_BLOCKS + SHALLOW_BLOCKS)

#define SANG 90
#define PLANE (SANG * NRAYS)         // 23040
#define PART_ELEMS (4 * 4 * PLANE)   // [stepgroup][batch][sangle][ray]
#define RED_ELEMS  (4 * PLANE)

typedef _Float16 half2v __attribute__((ext_vector_type(2)));

__device__ __forceinline__ float hdot(unsigned int p, half2v w, float acc) {
#if __has_builtin(__builtin_amdgcn_fdot2)
    return __builtin_amdgcn_fdot2(__builtin_bit_cast(half2v, p), w, acc, false);
#else
    half2v v = __builtin_bit_cast(half2v, p);
    return acc + (float)v.x * (float)w.x + (float)v.y * (float)w.y;
#endif
}

// pre-pass: imgs[4][256][256] -> padded pair image.
// ppx[y][x] = { half2(v_b(y-1,x-1), v_b(y-1,x)) for b=0..3 }  (0 outside image)
__global__ __launch_bounds__(256) void pad_pairs(
    const float* __restrict__ imgs, uint4* __restrict__ timg)
{
    const int idx = blockIdx.x * 256 + threadIdx.x;
    if (idx >= PADN) return;
    const int y = idx / PITCH, x = idx - y * PITCH;
    const int iy = y - 1;
    const bool ry = (unsigned)iy < (unsigned)RES;
    const bool r0 = ry && ((unsigned)(x - 1) < (unsigned)RES);
    const bool r1 = ry && ((unsigned)x < (unsigned)RES);
    const int s0 = iy * RES + (x - 1);
    const int s1 = iy * RES + x;

    unsigned int u[4];
#pragma unroll
    for (int b = 0; b < 4; ++b) {
        const float v0 = r0 ? imgs[b * NPIX + s0] : 0.0f;
        const float v1 = r1 ? imgs[b * NPIX + s1] : 0.0f;
        half2v h; h.x = (_Float16)v0; h.y = (_Float16)v1;
        u[b] = __builtin_bit_cast(unsigned int, h);
    }
    timg[idx] = make_uint4(u[0], u[1], u[2], u[3]);
}

struct Geom { float srx, sry, ddx, ddy, scale; };

__device__ __forceinline__ Geom make_geom(const float* __restrict__ angles,
                                          const float* __restrict__ rays,
                                          int a, int r)
{
    float sn, cs;
    sincosf(angles[a], &sn, &cs);
    const float4 ray = reinterpret_cast<const float4*>(rays)[r];
    const float dxr = ray.z - ray.x, dyr = ray.w - ray.y;
    const float len = sqrtf(dxr * dxr + dyr * dyr);
    Geom g;
    g.srx = cs * ray.x - sn * ray.y + 127.5f;
    g.sry = sn * ray.x + cs * ray.y + 127.5f;
    g.ddx = (cs * ray.z - sn * ray.w + 127.5f) - g.srx;
    g.ddy = (sn * ray.z + cs * ray.w + 127.5f) - g.sry;
    g.scale = len * (1.0f / RES);
    return g;
}

// one bilinear sample at (fx,fy): 2 uint4 gathers (row0/row1 pair image),
// 8 v_dot2_f32_f16 accumulates (4 batches x 2 rows)
__device__ __forceinline__ void samp2(
    const uint4* __restrict__ timg, float fx, float fy,
    float& a0, float& a1, float& a2, float& a3)
{
    const float x0f = floorf(fx), y0f = floorf(fy);
    const float wx = fx - x0f, wy = fy - y0f;

    const int idx = (int)y0f * PITCH + (int)x0f + (PITCH + 1);
    const uint4 row0 = timg[idx];
    const uint4 row1 = timg[idx + PITCH];

    const float w11 = wx * wy;
    const float w01 = wx - w11;
    const float w10 = wy - w11;
    const float w00 = (1.0f - wx) - w10;

    half2v wa; wa.x = (_Float16)w00; wa.y = (_Float16)w01;
    half2v wb; wb.x = (_Float16)w10; wb.y = (_Float16)w11;

    a0 = hdot(row0.x, wa, hdot(row1.x, wb, a0));
    a1 = hdot(row0.y, wa, hdot(row1.y, wb, a1));
    a2 = hdot(row0.z, wa, hdot(row1.z, wb, a2));
    a3 = hdot(row0.w, wa, hdot(row1.w, wb, a3));
}

__global__ __launch_bounds__(512) void radon_main(
    const uint4*  __restrict__ timg,
    const float*  __restrict__ angles,
    const float*  __restrict__ rays,
    float*        __restrict__ out,
    float*        __restrict__ part)
{
    const int bid = blockIdx.x;
    const int tid = threadIdx.x;

    if (bid < STEEP_BLOCKS) {
        // lanes = steps along ray (x-contiguous at steep angles); wave = 2 rays x 32 steps
        const int a    = (bid >> 4) + 45;          // 45..134
        const int rq   = bid & 15;
        const int w    = tid >> 6;
        const int lane = tid & 63;
        const int half = lane >> 5;
        const int sub  = lane & 31;
        const int r    = rq * 16 + w * 2 + half;

        const Geom g = make_geom(angles, rays, a, r);
        float a0 = 0.f, a1 = 0.f, a2 = 0.f, a3 = 0.f;

        // k_j = j*32 + sub : incremental stepping, dfx = ddx/8
        float fx = fmaf(((float)sub + 0.5f) * (1.0f / RES), g.ddx, g.srx);
        float fy = fmaf(((float)sub + 0.5f) * (1.0f / RES), g.ddy, g.sry);
        const float dfx = g.ddx * 0.125f;
        const float dfy = g.ddy * 0.125f;

#pragma unroll
        for (int j = 0; j < 8; ++j) {
            samp2(timg, fx, fy, a0, a1, a2, a3);
            fx += dfx; fy += dfy;
        }

#pragma unroll
        for (int m = 1; m < 32; m <<= 1) {
            a0 += __shfl_xor(a0, m, 64);
            a1 += __shfl_xor(a1, m, 64);
            a2 += __shfl_xor(a2, m, 64);
            a3 += __shfl_xor(a3, m, 64);
        }
        if (sub == 0) {
            const int base = a * NRAYS + r;
            out[0 * OUTP + base] = a0 * g.scale;
            out[1 * OUTP + base] = a1 * g.scale;
            out[2 * OUTP + base] = a2 * g.scale;
            out[3 * OUTP + base] = a3 * g.scale;
        }
    } else {
        // lanes = rays (x-contiguous at shallow angles); 4 step-groups -> partials
        const int b  = bid - STEEP_BLOCKS;
        const int sg = b & 3;
        const int rg = (b >> 2) & 3;
        const int as = b >> 4;
        const int a  = (as < 45) ? as : as + 90;
        const int tx = tid & 63;
        const int ty = tid >> 6;
        const int r  = rg * 64 + tx;

        const Geom g = make_geom(angles, rays, a, r);
        float a0 = 0.f, a1 = 0.f, a2 = 0.f, a3 = 0.f;

        const int k0 = sg * 64 + ty * 8;
        float fx = fmaf(((float)k0 + 0.5f) * (1.0f / RES), g.ddx, g.srx);
        float fy = fmaf(((float)k0 + 0.5f) * (1.0f / RES), g.ddy, g.sry);
        const float dfx = g.ddx * (1.0f / RES);
        const float dfy = g.ddy * (1.0f / RES);

#pragma unroll
        for (int j = 0; j < 8; ++j) {
            samp2(timg, fx, fy, a0, a1, a2, a3);
            fx += dfx; fy += dfy;
        }

        __shared__ float4 red[8][64];
        red[ty][tx] = make_float4(a0, a1, a2, a3);
        __syncthreads();

        if (ty == 0) {
#pragma unroll
            for (int j = 1; j < 8; ++j) {
                const float4 v = red[j][tx];
                a0 += v.x; a1 += v.y; a2 += v.z; a3 += v.w;
            }
            float* p = part + (size_t)sg * 4 * PLANE;
            const int base = as * NRAYS + r;
            p[0 * PLANE + base] = a0 * g.scale;
            p[1 * PLANE + base] = a1 * g.scale;
            p[2 * PLANE + base] = a2 * g.scale;
            p[3 * PLANE + base] = a3 * g.scale;
        }
    }
}

__global__ __launch_bounds__(256) void radon_reduce(
    const float* __restrict__ part, float* __restrict__ out)
{
    const int i = blockIdx.x * 256 + threadIdx.x;
    if (i >= RED_ELEMS) return;
    const int b    = i / PLANE;
    const int rest = i - b * PLANE;
    const int as   = rest >> 8;
    const int ray  = rest & 255;
    const int a    = (as < 45) ? as : as + 90;

    float s = 0.f;
#pragma unroll
    for (int sg = 0; sg < 4; ++sg)
        s += part[(sg * 4 + b) * PLANE + rest];
    out[b * OUTP + a * NRAYS + ray] = s;
}

// ---- fallback (no workspace): simple clamped per-ray kernel, known-correct, f32
__global__ __launch_bounds__(256) void radon_simple(
    const float* __restrict__ imgs,
    const float* __restrict__ angles,
    const float* __restrict__ rays,
    float* __restrict__ out)
{
    const int a = blockIdx.x;
    const int r = threadIdx.x;
    const Geom g = make_geom(angles, rays, a, r);
    float a0 = 0.f, a1 = 0.f, a2 = 0.f, a3 = 0.f;
    for (int k = 0; k < RES; ++k) {
        const float t  = ((float)k + 0.5f) * (1.0f / RES);
        const float fx = fmaf(t, g.ddx, g.srx);
        const float fy = fmaf(t, g.ddy, g.sry);
        const float x0f = floorf(fx), y0f = floorf(fy);
        const float wx = fx - x0f, wy = fy - y0f;
        const int x0 = (int)x0f, y0 = (int)y0f;
        const bool vx0 = (unsigned)x0 < (unsigned)RES;
        const bool vx1 = (unsigned)(x0 + 1) < (unsigned)RES;
        const bool vy0 = (unsigned)y0 < (unsigned)RES;
        const bool vy1 = (unsigned)(y0 + 1) < (unsigned)RES;
        const int x0c = min(max(x0, 0), RES - 1), x1c = min(max(x0 + 1, 0), RES - 1);
        const int y0c = min(max(y0, 0), RES - 1), y1c = min(max(y0 + 1, 0), RES - 1);
        const float omwx = 1.0f - wx, omwy = 1.0f - wy;
        const float w00 = (vx0 && vy0) ? omwx * omwy : 0.f;
        const float w01 = (vx1 && vy0) ? wx * omwy : 0.f;
        const float w10 = (vx0 && vy1) ? omwx * wy : 0.f;
        const float w11 = (vx1 && vy1) ? wx * wy : 0.f;
        const int i00 = y0c * RES + x0c, i01 = y0c * RES + x1c;
        const int i10 = y1c * RES + x0c, i11 = y1c * RES + x1c;
        a0 = fmaf(w00, imgs[i00], fmaf(w01, imgs[i01], fmaf(w10, imgs[i10], fmaf(w11, imgs[i11], a0))));
        a1 = fmaf(w00, imgs[NPIX + i00], fmaf(w01, imgs[NPIX + i01], fmaf(w10, imgs[NPIX + i10], fmaf(w11, imgs[NPIX + i11], a1))));
        a2 = fmaf(w00, imgs[2 * NPIX + i00], fmaf(w01, imgs[2 * NPIX + i01], fmaf(w10, imgs[2 * NPIX + i10], fmaf(w11, imgs[2 * NPIX + i11], a2))));
        a3 = fmaf(w00, imgs[3 * NPIX + i00], fmaf(w01, imgs[3 * NPIX + i01], fmaf(w10, imgs[3 * NPIX + i10], fmaf(w11, imgs[3 * NPIX + i11], a3))));
    }
    const int base = a * NRAYS + r;
    out[0 * OUTP + base] = a0 * g.scale;
    out[1 * OUTP + base] = a1 * g.scale;
    out[2 * OUTP + base] = a2 * g.scale;
    out[3 * OUTP + base] = a3 * g.scale;
}

extern "C" void kernel_launch(void* const* d_in, const int* in_sizes, int n_in,
                              void* d_out, int out_size, void* d_ws, size_t ws_size,
                              hipStream_t stream) {
    const float* imgs   = (const float*)d_in[0];
    const float* angles = (const float*)d_in[1];
    const float* rays   = (const float*)d_in[2];
    float* out = (float*)d_out;

    const size_t timg_bytes = (size_t)PADN * sizeof(uint4);
    const size_t need = timg_bytes + (size_t)PART_ELEMS * sizeof(float);

    if (ws_size >= need) {
        uint4* timg = (uint4*)d_ws;
        float* part = (float*)((char*)d_ws + timg_bytes);
        pad_pairs<<<(PADN + 255) / 256, 256, 0, stream>>>(imgs, timg);
        radon_main<<<TOTAL_BLOCKS, 512, 0, stream>>>(timg, angles, rays, out, part);
        radon_reduce<<<(RED_ELEMS + 255) / 256, 256, 0, stream>>>(part, out);
    } else {
        radon_simple<<<NANG, NRAYS, 0, stream>>>(imgs, angles, rays, out);
    }
}

// Round 8
// 35.047 us; speedup vs baseline: 1.6955x; 1.0178x over previous
//
#include <hip/hip_runtime.h>

#define RES   256
#define NANG  180
#define NRAYS 256
#define NPIX  (RES * RES)
#define OUTP  (NANG * NRAYS)

#define PITCH 258                    // padded row pitch (uint4 elems)
#define PADN  (PITCH * PITCH)        // 66564 padded pixels

// shallow blocks first (fat: 16 samples/thread), then steep (8 samples/thread)
#define SHALLOW_BLOCKS (90 * 8)      // 90 angles x 8 groups of 32 rays, all 256 steps
#define STEEP_BLOCKS   (90 * 16)     // 90 angles x 16 ray-quads(16): wave = 2 rays x 32 steps
#define TOTAL_BLOCKS   (SHALLOW_BLOCKS + STEEP_BLOCKS)

typedef _Float16 half2v __attribute__((ext_vector_type(2)));

__device__ __forceinline__ float hdot(unsigned int p, half2v w, float acc) {
#if __has_builtin(__builtin_amdgcn_fdot2)
    return __builtin_amdgcn_fdot2(__builtin_bit_cast(half2v, p), w, acc, false);
#else
    half2v v = __builtin_bit_cast(half2v, p);
    return acc + (float)v.x * (float)w.x + (float)v.y * (float)w.y;
#endif
}

// pre-pass: imgs[4][256][256] -> padded pair image.
// ppx[y][x] = { half2(v_b(y-1,x-1), v_b(y-1,x)) for b=0..3 }  (0 outside image)
__global__ __launch_bounds__(256) void pad_pairs(
    const float* __restrict__ imgs, uint4* __restrict__ timg)
{
    const int idx = blockIdx.x * 256 + threadIdx.x;
    if (idx >= PADN) return;
    const int y = idx / PITCH, x = idx - y * PITCH;
    const int iy = y - 1;
    const bool ry = (unsigned)iy < (unsigned)RES;
    const bool r0 = ry && ((unsigned)(x - 1) < (unsigned)RES);
    const bool r1 = ry && ((unsigned)x < (unsigned)RES);
    const int s0 = iy * RES + (x - 1);
    const int s1 = iy * RES + x;

    unsigned int u[4];
#pragma unroll
    for (int b = 0; b < 4; ++b) {
        const float v0 = r0 ? imgs[b * NPIX + s0] : 0.0f;
        const float v1 = r1 ? imgs[b * NPIX + s1] : 0.0f;
        half2v h; h.x = (_Float16)v0; h.y = (_Float16)v1;
        u[b] = __builtin_bit_cast(unsigned int, h);
    }
    timg[idx] = make_uint4(u[0], u[1], u[2], u[3]);
}

struct Geom { float srx, sry, ddx, ddy, scale; };

__device__ __forceinline__ Geom make_geom(const float* __restrict__ angles,
                                          const float* __restrict__ rays,
                                          int a, int r)
{
    float sn, cs;
    sincosf(angles[a], &sn, &cs);
    const float4 ray = reinterpret_cast<const float4*>(rays)[r];
    const float dxr = ray.z - ray.x, dyr = ray.w - ray.y;
    const float len = sqrtf(dxr * dxr + dyr * dyr);
    Geom g;
    g.srx = cs * ray.x - sn * ray.y + 127.5f;
    g.sry = sn * ray.x + cs * ray.y + 127.5f;
    g.ddx = (cs * ray.z - sn * ray.w + 127.5f) - g.srx;
    g.ddy = (sn * ray.z + cs * ray.w + 127.5f) - g.sry;
    g.scale = len * (1.0f / RES);
    return g;
}

// one bilinear sample at (fx,fy): 2 uint4 gathers, 8 v_dot2_f32_f16
__device__ __forceinline__ void samp2(
    const uint4* __restrict__ timg, float fx, float fy,
    float& a0, float& a1, float& a2, float& a3)
{
    const float x0f = floorf(fx), y0f = floorf(fy);
    const float wx = fx - x0f, wy = fy - y0f;

    const int idx = (int)y0f * PITCH + (int)x0f + (PITCH + 1);
    const uint4 row0 = timg[idx];
    const uint4 row1 = timg[idx + PITCH];

    const float w11 = wx * wy;
    const float w01 = wx - w11;
    const float w10 = wy - w11;
    const float w00 = (1.0f - wx) - w10;

    half2v wa; wa.x = (_Float16)w00; wa.y = (_Float16)w01;
    half2v wb; wb.x = (_Float16)w10; wb.y = (_Float16)w11;

    a0 = hdot(row0.x, wa, hdot(row1.x, wb, a0));
    a1 = hdot(row0.y, wa, hdot(row1.y, wb, a1));
    a2 = hdot(row0.z, wa, hdot(row1.z, wb, a2));
    a3 = hdot(row0.w, wa, hdot(row1.w, wb, a3));
}

__global__ __launch_bounds__(512, 4) void radon_main(
    const uint4*  __restrict__ timg,
    const float*  __restrict__ angles,
    const float*  __restrict__ rays,
    float*        __restrict__ out)
{
    const int bid = blockIdx.x;
    const int tid = threadIdx.x;

    if (bid < SHALLOW_BLOCKS) {
        // lanes = rays (x-contiguous at shallow angles).
        // block = 32 rays x 256 steps; thread (tx,ty): 16 samples at
        // k = sg*128 + ty*8 + j  (sg=0..1, j=0..7); LDS reduce over ty.
        const int as = bid >> 3;                  // 0..89
        const int rg = bid & 7;                   // group of 32 rays
        const int a  = (as < 45) ? as : as + 90;
        const int tx = tid & 31;                  // ray lane
        const int ty = tid >> 5;                  // step chunk 0..15
        const int r  = rg * 32 + tx;

        const Geom g = make_geom(angles, rays, a, r);
        float acc[4] = {0.f, 0.f, 0.f, 0.f};

        const float dfx = g.ddx * (1.0f / RES);
        const float dfy = g.ddy * (1.0f / RES);
        float fx = fmaf(((float)(ty * 8) + 0.5f) * (1.0f / RES), g.ddx, g.srx);
        float fy = fmaf(((float)(ty * 8) + 0.5f) * (1.0f / RES), g.ddy, g.sry);

#pragma unroll
        for (int sg = 0; sg < 2; ++sg) {
#pragma unroll
            for (int j = 0; j < 8; ++j) {
                samp2(timg, fx, fy, acc[0], acc[1], acc[2], acc[3]);
                fx += dfx; fy += dfy;
            }
            // jump 120 steps to the next 128-step half
            fx += g.ddx * (120.0f / RES);
            fy += g.ddy * (120.0f / RES);
        }

        // transposed LDS reduce: red[b][ty][tx], conflict-free on read
        __shared__ float red[4][16][32];
#pragma unroll
        for (int b = 0; b < 4; ++b) red[b][ty][tx] = acc[b];
        __syncthreads();

        if (tid < 128) {
            const int b  = tid >> 5;
            const int t2 = tid & 31;
            float s = 0.f;
#pragma unroll
            for (int j = 0; j < 16; ++j) s += red[b][j][t2];
            out[b * OUTP + a * NRAYS + rg * 32 + t2] = s * g.scale;
        }
    } else {
        // lanes = steps along ray (x-contiguous at steep angles); wave = 2 rays x 32 steps
        const int b2   = bid - SHALLOW_BLOCKS;
        const int a    = (b2 >> 4) + 45;          // 45..134
        const int rq   = b2 & 15;
        const int w    = tid >> 6;
        const int lane = tid & 63;
        const int half = lane >> 5;
        const int sub  = lane & 31;
        const int r    = rq * 16 + w * 2 + half;

        const Geom g = make_geom(angles, rays, a, r);
        float a0 = 0.f, a1 = 0.f, a2 = 0.f, a3 = 0.f;

        float fx = fmaf(((float)sub + 0.5f) * (1.0f / RES), g.ddx, g.srx);
        float fy = fmaf(((float)sub + 0.5f) * (1.0f / RES), g.ddy, g.sry);
        const float dfx = g.ddx * 0.125f;
        const float dfy = g.ddy * 0.125f;

#pragma unroll
        for (int j = 0; j < 8; ++j) {
            samp2(timg, fx, fy, a0, a1, a2, a3);
            fx += dfx; fy += dfy;
        }

#pragma unroll
        for (int m = 1; m < 32; m <<= 1) {
            a0 += __shfl_xor(a0, m, 64);
            a1 += __shfl_xor(a1, m, 64);
            a2 += __shfl_xor(a2, m, 64);
            a3 += __shfl_xor(a3, m, 64);
        }
        if (sub == 0) {
            const int base = a * NRAYS + r;
            out[0 * OUTP + base] = a0 * g.scale;
            out[1 * OUTP + base] = a1 * g.scale;
            out[2 * OUTP + base] = a2 * g.scale;
            out[3 * OUTP + base] = a3 * g.scale;
        }
    }
}

// ---- fallback (no workspace): simple clamped per-ray kernel, known-correct, f32
__global__ __launch_bounds__(256) void radon_simple(
    const float* __restrict__ imgs,
    const float* __restrict__ angles,
    const float* __restrict__ rays,
    float* __restrict__ out)
{
    const int a = blockIdx.x;
    const int r = threadIdx.x;
    const Geom g = make_geom(angles, rays, a, r);
    float a0 = 0.f, a1 = 0.f, a2 = 0.f, a3 = 0.f;
    for (int k = 0; k < RES; ++k) {
        const float t  = ((float)k + 0.5f) * (1.0f / RES);
        const float fx = fmaf(t, g.ddx, g.srx);
        const float fy = fmaf(t, g.ddy, g.sry);
        const float x0f = floorf(fx), y0f = floorf(fy);
        const float wx = fx - x0f, wy = fy - y0f;
        const int x0 = (int)x0f, y0 = (int)y0f;
        const bool vx0 = (unsigned)x0 < (unsigned)RES;
        const bool vx1 = (unsigned)(x0 + 1) < (unsigned)RES;
        const bool vy0 = (unsigned)y0 < (unsigned)RES;
        const bool vy1 = (unsigned)(y0 + 1) < (unsigned)RES;
        const int x0c = min(max(x0, 0), RES - 1), x1c = min(max(x0 + 1, 0), RES - 1);
        const int y0c = min(max(y0, 0), RES - 1), y1c = min(max(y0 + 1, 0), RES - 1);
        const float omwx = 1.0f - wx, omwy = 1.0f - wy;
        const float w00 = (vx0 && vy0) ? omwx * omwy : 0.f;
        const float w01 = (vx1 && vy0) ? wx * omwy : 0.f;
        const float w10 = (vx0 && vy1) ? omwx * wy : 0.f;
        const float w11 = (vx1 && vy1) ? wx * wy : 0.f;
        const int i00 = y0c * RES + x0c, i01 = y0c * RES + x1c;
        const int i10 = y1c * RES + x0c, i11 = y1c * RES + x1c;
        a0 = fmaf(w00, imgs[i00], fmaf(w01, imgs[i01], fmaf(w10, imgs[i10], fmaf(w11, imgs[i11], a0))));
        a1 = fmaf(w00, imgs[NPIX + i00], fmaf(w01, imgs[NPIX + i01], fmaf(w10, imgs[NPIX + i10], fmaf(w11, imgs[NPIX + i11], a1))));
        a2 = fmaf(w00, imgs[2 * NPIX + i00], fmaf(w01, imgs[2 * NPIX + i01], fmaf(w10, imgs[2 * NPIX + i10], fmaf(w11, imgs[2 * NPIX + i11], a2))));
        a3 = fmaf(w00, imgs[3 * NPIX + i00], fmaf(w01, imgs[3 * NPIX + i01], fmaf(w10, imgs[3 * NPIX + i10], fmaf(w11, imgs[3 * NPIX + i11], a3))));
    }
    const int base = a * NRAYS + r;
    out[0 * OUTP + base] = a0 * g.scale;
    out[1 * OUTP + base] = a1 * g.scale;
    out[2 * OUTP + base] = a2 * g.scale;
    out[3 * OUTP + base] = a3 * g.scale;
}

extern "C" void kernel_launch(void* const* d_in, const int* in_sizes, int n_in,
                              void* d_out, int out_size, void* d_ws, size_t ws_size,
                              hipStream_t stream) {
    const float* imgs   = (const float*)d_in[0];
    const float* angles = (const float*)d_in[1];
    const float* rays   = (const float*)d_in[2];
    float* out = (float*)d_out;

    const size_t need = (size_t)PADN * sizeof(uint4);

    if (ws_size >= need) {
        uint4* timg = (uint4*)d_ws;
        pad_pairs<<<(PADN + 255) / 256, 256, 0, stream>>>(imgs, timg);
        radon_main<<<TOTAL_BLOCKS, 512, 0, stream>>>(timg, angles, rays, out);
    } else {
        radon_simple<<<NANG, NRAYS, 0, stream>>>(imgs, angles, rays, out);
    }
}

// Round 9
// 34.612 us; speedup vs baseline: 1.7168x; 1.0126x over previous
//
#include <hip/hip_runtime.h>

#define RES   256
#define NANG  180
#define NRAYS 256
#define NPIX  (RES * RES)
#define OUTP  (NANG * NRAYS)

#define PITCH 258                    // padded row pitch (uint4 elems)
#define PADN  (PITCH * PITCH)        // 66564 padded pixels

// shallow blocks first (fat: 16 samples/thread), then steep (8 samples/thread)
#define SHALLOW_BLOCKS (90 * 8)      // 90 angles x 8 groups of 32 rays, all 256 steps
#define STEEP_BLOCKS   (90 * 16)     // 90 angles x 16 ray-quads(16): wave = 2 rays x 32 steps
#define TOTAL_BLOCKS   (SHALLOW_BLOCKS + STEEP_BLOCKS)

typedef _Float16 half2v __attribute__((ext_vector_type(2)));

__device__ __forceinline__ float hdot(unsigned int p, half2v w, float acc) {
#if __has_builtin(__builtin_amdgcn_fdot2)
    return __builtin_amdgcn_fdot2(__builtin_bit_cast(half2v, p), w, acc, false);
#else
    half2v v = __builtin_bit_cast(half2v, p);
    return acc + (float)v.x * (float)w.x + (float)v.y * (float)w.y;
#endif
}

// pre-pass: imgs[4][256][256] -> padded pair image.
// ppx[y][x] = { half2(v_b(y-1,x-1), v_b(y-1,x)) for b=0..3 }  (0 outside image)
__global__ __launch_bounds__(256) void pad_pairs(
    const float* __restrict__ imgs, uint4* __restrict__ timg)
{
    const int idx = blockIdx.x * 256 + threadIdx.x;
    if (idx >= PADN) return;
    const int y = idx / PITCH, x = idx - y * PITCH;
    const int iy = y - 1;
    const bool ry = (unsigned)iy < (unsigned)RES;
    const bool r0 = ry && ((unsigned)(x - 1) < (unsigned)RES);
    const bool r1 = ry && ((unsigned)x < (unsigned)RES);
    const int s0 = iy * RES + (x - 1);
    const int s1 = iy * RES + x;

    unsigned int u[4];
#pragma unroll
    for (int b = 0; b < 4; ++b) {
        const float v0 = r0 ? imgs[b * NPIX + s0] : 0.0f;
        const float v1 = r1 ? imgs[b * NPIX + s1] : 0.0f;
        half2v h; h.x = (_Float16)v0; h.y = (_Float16)v1;
        u[b] = __builtin_bit_cast(unsigned int, h);
    }
    timg[idx] = make_uint4(u[0], u[1], u[2], u[3]);
}

struct Geom { float srx, sry, ddx, ddy, scale; };

__device__ __forceinline__ Geom make_geom(const float* __restrict__ angles,
                                          const float* __restrict__ rays,
                                          int a, int r)
{
    float sn, cs;
    sincosf(angles[a], &sn, &cs);
    const float4 ray = reinterpret_cast<const float4*>(rays)[r];
    const float dxr = ray.z - ray.x, dyr = ray.w - ray.y;
    const float len = sqrtf(dxr * dxr + dyr * dyr);
    Geom g;
    g.srx = cs * ray.x - sn * ray.y + 127.5f;
    g.sry = sn * ray.x + cs * ray.y + 127.5f;
    g.ddx = (cs * ray.z - sn * ray.w + 127.5f) - g.srx;
    g.ddy = (sn * ray.z + cs * ray.w + 127.5f) - g.sry;
    g.scale = len * (1.0f / RES);
    return g;
}

// 8 bilinear samples, batched: phase A issues all 16 uint4 gathers into
// registers (load ILP), phase B does the fdot2 math. acc split 2-way to
// shorten the fdot2 dependency chain.
__device__ __forceinline__ void sample8(
    const uint4* __restrict__ timg,
    float& fx, float& fy, float dfx, float dfy,
    float acc0[4], float acc1[4])
{
    uint4 r0[8], r1[8];
    float wxv[8], wyv[8];

#pragma unroll
    for (int j = 0; j < 8; ++j) {
        const float x0f = floorf(fx), y0f = floorf(fy);
        wxv[j] = fx - x0f;
        wyv[j] = fy - y0f;
        const int idx = (int)y0f * PITCH + (int)x0f + (PITCH + 1);
        r0[j] = timg[idx];
        r1[j] = timg[idx + PITCH];
        fx += dfx; fy += dfy;
    }

#pragma unroll
    for (int j = 0; j < 8; ++j) {
        const float wx = wxv[j], wy = wyv[j];
        const float w11 = wx * wy;
        const float w01 = wx - w11;
        const float w10 = wy - w11;
        const float w00 = (1.0f - wx) - w10;

        half2v wa; wa.x = (_Float16)w00; wa.y = (_Float16)w01;
        half2v wb; wb.x = (_Float16)w10; wb.y = (_Float16)w11;

        float* acc = (j & 1) ? acc1 : acc0;
        acc[0] = hdot(r0[j].x, wa, hdot(r1[j].x, wb, acc[0]));
        acc[1] = hdot(r0[j].y, wa, hdot(r1[j].y, wb, acc[1]));
        acc[2] = hdot(r0[j].z, wa, hdot(r1[j].z, wb, acc[2]));
        acc[3] = hdot(r0[j].w, wa, hdot(r1[j].w, wb, acc[3]));
    }
}

__global__ __launch_bounds__(512, 4) void radon_main(
    const uint4*  __restrict__ timg,
    const float*  __restrict__ angles,
    const float*  __restrict__ rays,
    float*        __restrict__ out)
{
    const int bid = blockIdx.x;
    const int tid = threadIdx.x;

    if (bid < SHALLOW_BLOCKS) {
        // lanes = rays (x-contiguous at shallow angles).
        // block = 32 rays x 256 steps; thread (tx,ty): 16 samples at
        // k = sg*128 + ty*8 + j  (sg=0..1, j=0..7); LDS reduce over ty.
        const int as = bid >> 3;                  // 0..89
        const int rg = bid & 7;                   // group of 32 rays
        const int a  = (as < 45) ? as : as + 90;
        const int tx = tid & 31;                  // ray lane
        const int ty = tid >> 5;                  // step chunk 0..15
        const int r  = rg * 32 + tx;

        const Geom g = make_geom(angles, rays, a, r);
        float acc0[4] = {0.f, 0.f, 0.f, 0.f};
        float acc1[4] = {0.f, 0.f, 0.f, 0.f};

        const float dfx = g.ddx * (1.0f / RES);
        const float dfy = g.ddy * (1.0f / RES);
        float fx = fmaf(((float)(ty * 8) + 0.5f) * (1.0f / RES), g.ddx, g.srx);
        float fy = fmaf(((float)(ty * 8) + 0.5f) * (1.0f / RES), g.ddy, g.sry);

        sample8(timg, fx, fy, dfx, dfy, acc0, acc1);
        // jump 120 steps to the second 128-step half
        fx += g.ddx * (120.0f / RES);
        fy += g.ddy * (120.0f / RES);
        sample8(timg, fx, fy, dfx, dfy, acc0, acc1);

        // transposed LDS reduce: red[b][ty][tx], conflict-free on read
        __shared__ float red[4][16][32];
#pragma unroll
        for (int b = 0; b < 4; ++b) red[b][ty][tx] = acc0[b] + acc1[b];
        __syncthreads();

        if (tid < 128) {
            const int b  = tid >> 5;
            const int t2 = tid & 31;
            float s = 0.f;
#pragma unroll
            for (int j = 0; j < 16; ++j) s += red[b][j][t2];
            out[b * OUTP + a * NRAYS + rg * 32 + t2] = s * g.scale;
        }
    } else {
        // lanes = steps along ray (x-contiguous at steep angles); wave = 2 rays x 32 steps
        const int b2   = bid - SHALLOW_BLOCKS;
        const int a    = (b2 >> 4) + 45;          // 45..134
        const int rq   = b2 & 15;
        const int w    = tid >> 6;
        const int lane = tid & 63;
        const int half = lane >> 5;
        const int sub  = lane & 31;
        const int r    = rq * 16 + w * 2 + half;

        const Geom g = make_geom(angles, rays, a, r);
        float acc0[4] = {0.f, 0.f, 0.f, 0.f};
        float acc1[4] = {0.f, 0.f, 0.f, 0.f};

        float fx = fmaf(((float)sub + 0.5f) * (1.0f / RES), g.ddx, g.srx);
        float fy = fmaf(((float)sub + 0.5f) * (1.0f / RES), g.ddy, g.sry);
        const float dfx = g.ddx * 0.125f;
        const float dfy = g.ddy * 0.125f;

        sample8(timg, fx, fy, dfx, dfy, acc0, acc1);

        float a0 = acc0[0] + acc1[0];
        float a1 = acc0[1] + acc1[1];
        float a2 = acc0[2] + acc1[2];
        float a3 = acc0[3] + acc1[3];

#pragma unroll
        for (int m = 1; m < 32; m <<= 1) {
            a0 += __shfl_xor(a0, m, 64);
            a1 += __shfl_xor(a1, m, 64);
            a2 += __shfl_xor(a2, m, 64);
            a3 += __shfl_xor(a3, m, 64);
        }
        if (sub == 0) {
            const int base = a * NRAYS + r;
            out[0 * OUTP + base] = a0 * g.scale;
            out[1 * OUTP + base] = a1 * g.scale;
            out[2 * OUTP + base] = a2 * g.scale;
            out[3 * OUTP + base] = a3 * g.scale;
        }
    }
}

// ---- fallback (no workspace): simple clamped per-ray kernel, known-correct, f32
__global__ __launch_bounds__(256) void radon_simple(
    const float* __restrict__ imgs,
    const float* __restrict__ angles,
    const float* __restrict__ rays,
    float* __restrict__ out)
{
    const int a = blockIdx.x;
    const int r = threadIdx.x;
    const Geom g = make_geom(angles, rays, a, r);
    float a0 = 0.f, a1 = 0.f, a2 = 0.f, a3 = 0.f;
    for (int k = 0; k < RES; ++k) {
        const float t  = ((float)k + 0.5f) * (1.0f / RES);
        const float fx = fmaf(t, g.ddx, g.srx);
        const float fy = fmaf(t, g.ddy, g.sry);
        const float x0f = floorf(fx), y0f = floorf(fy);
        const float wx = fx - x0f, wy = fy - y0f;
        const int x0 = (int)x0f, y0 = (int)y0f;
        const bool vx0 = (unsigned)x0 < (unsigned)RES;
        const bool vx1 = (unsigned)(x0 + 1) < (unsigned)RES;
        const bool vy0 = (unsigned)y0 < (unsigned)RES;
        const bool vy1 = (unsigned)(y0 + 1) < (unsigned)RES;
        const int x0c = min(max(x0, 0), RES - 1), x1c = min(max(x0 + 1, 0), RES - 1);
        const int y0c = min(max(y0, 0), RES - 1), y1c = min(max(y0 + 1, 0), RES - 1);
        const float omwx = 1.0f - wx, omwy = 1.0f - wy;
        const float w00 = (vx0 && vy0) ? omwx * omwy : 0.f;
        const float w01 = (vx1 && vy0) ? wx * omwy : 0.f;
        const float w10 = (vx0 && vy1) ? omwx * wy : 0.f;
        const float w11 = (vx1 && vy1) ? wx * wy : 0.f;
        const int i00 = y0c * RES + x0c, i01 = y0c * RES + x1c;
        const int i10 = y1c * RES + x0c, i11 = y1c * RES + x1c;
        a0 = fmaf(w00, imgs[i00], fmaf(w01, imgs[i01], fmaf(w10, imgs[i10], fmaf(w11, imgs[i11], a0))));
        a1 = fmaf(w00, imgs[NPIX + i00], fmaf(w01, imgs[NPIX + i01], fmaf(w10, imgs[NPIX + i10], fmaf(w11, imgs[NPIX + i11], a1))));
        a2 = fmaf(w00, imgs[2 * NPIX + i00], fmaf(w01, imgs[2 * NPIX + i01], fmaf(w10, imgs[2 * NPIX + i10], fmaf(w11, imgs[2 * NPIX + i11], a2))));
        a3 = fmaf(w00, imgs[3 * NPIX + i00], fmaf(w01, imgs[3 * NPIX + i01], fmaf(w10, imgs[3 * NPIX + i10], fmaf(w11, imgs[3 * NPIX + i11], a3))));
    }
    const int base = a * NRAYS + r;
    out[0 * OUTP + base] = a0 * g.scale;
    out[1 * OUTP + base] = a1 * g.scale;
    out[2 * OUTP + base] = a2 * g.scale;
    out[3 * OUTP + base] = a3 * g.scale;
}

extern "C" void kernel_launch(void* const* d_in, const int* in_sizes, int n_in,
                              void* d_out, int out_size, void* d_ws, size_t ws_size,
                              hipStream_t stream) {
    const float* imgs   = (const float*)d_in[0];
    const float* angles = (const float*)d_in[1];
    const float* rays   = (const float*)d_in[2];
    float* out = (float*)d_out;

    const size_t need = (size_t)PADN * sizeof(uint4);

    if (ws_size >= need) {
        uint4* timg = (uint4*)d_ws;
        pad_pairs<<<(PADN + 255) / 256, 256, 0, stream>>>(imgs, timg);
        radon_main<<<TOTAL_BLOCKS, 512, 0, stream>>>(timg, angles, rays, out);
    } else {
        radon_simple<<<NANG, NRAYS, 0, stream>>>(imgs, angles, rays, out);
    }
}